// Round 13
// baseline (1836.177 us; speedup 1.0000x reference)
//
#include <hip/hip_runtime.h>
#include <hip/hip_cooperative_groups.h>

namespace cg = cooperative_groups;

#define N_NODES 100000
#define E_EDGES 1600000
#define E_TOT   1700000   // edges + self loops
#define FDIM    128       // F_IN and HEADS*HID
#define C2      10        // classes
#define YPAD    16        // yl/yr row stride (one 64B line)
#define NEG     0.2f
#define LOG2E   1.44269504088896f
#define PCLAMP  80.0f

#define NT1     ((N_NODES + 63) / 64)        // 1563 gemm tiles
#define NAGG    ((N_NODES + 3) / 4)          // 25000 agg units (4 nodes each)
#define NDEG    ((E_TOT + 255) / 256)        // 6641 edge chunks
#define NWT     128                          // 32768 / 256

typedef __attribute__((ext_vector_type(8))) short short8;
typedef __attribute__((ext_vector_type(4))) float f32x4;

// 16-lane row reduction via DPP (pure VALU, no LDS pipe)
template <int CTRL>
__device__ __forceinline__ float dpp_add(float x) {
  return x + __int_as_float(
      __builtin_amdgcn_update_dpp(0, __float_as_int(x), CTRL, 0xF, 0xF, true));
}
__device__ __forceinline__ float row16_sum(float p) {
  p = dpp_add<0xB1>(p);
  p = dpp_add<0x4E>(p);
  p = dpp_add<0x141>(p);
  p = dpp_add<0x140>(p);
  return p;
}

__device__ __forceinline__ unsigned short f2bf(float f) {
  unsigned int u = __float_as_uint(f);
  u += 0x7FFFu + ((u >> 16) & 1u);
  return (unsigned short)(u >> 16);
}
__device__ __forceinline__ float2 up2(unsigned int v) {
  return make_float2(__uint_as_float(v << 16), __uint_as_float(v & 0xFFFF0000u));
}

#define SCAN_ITEMS 8
#define SCAN_CHUNK 2048
#define SCAN_NBLK  ((N_NODES + SCAN_CHUNK - 1) / SCAN_CHUNK)   // 49

// =================== unit bodies (shared by mega + fallback kernels) ===================

__device__ __forceinline__ void wt_unit(int u, int t, const float* W1l, const float* W1r,
                                        unsigned short* Wt) {
  int i = u * 256 + t;                      // u < 128 -> i < 32768
  int n = i & 255, k = i >> 8;
  float v = (n < 128) ? W1l[k * 128 + n] : W1r[k * 128 + (n - 128)];
  Wt[n * 128 + k] = f2bf(v);                // B^T layout
}

__device__ __forceinline__ void deg_unit(int u, int t, const int* ei, int* cnt, int* epos) {
  int tid = u * 256 + t;
  if (tid < E_TOT) {
    int d = (tid < E_EDGES) ? ei[E_EDGES + tid] : (tid - E_EDGES);
    epos[tid] = atomicAdd(&cnt[d], 1);
  }
}

__device__ __forceinline__ void scan1_unit(int b, int t, const int* cnt, int* bsum, int* sd) {
  int base = b * SCAN_CHUNK + t * SCAN_ITEMS;
  int s = 0;
#pragma unroll
  for (int i = 0; i < SCAN_ITEMS; i++) {
    int idx = base + i;
    if (idx < N_NODES) s += cnt[idx];
  }
  sd[t] = s; __syncthreads();
  for (int o = 128; o > 0; o >>= 1) {
    if (t < o) sd[t] += sd[t + o];
    __syncthreads();
  }
  if (t == 0) bsum[b] = sd[0];
  __syncthreads();
}

__device__ __forceinline__ void scan2_unit(int t, const int* bsum, int* boff) {
  // 64 lanes (wave 0)
  int v = (t < SCAN_NBLK) ? bsum[t] : 0;
  int orig = v;
  for (int o = 1; o < 64; o <<= 1) {
    int u = __shfl_up(v, o);
    if (t >= o) v += u;
  }
  if (t < SCAN_NBLK) boff[t] = v - orig;
}

__device__ __forceinline__ void scan3_unit(int b, int t, const int* cnt, const int* boff,
                                           int* row_ptr, int* sd) {
  int base = b * SCAN_CHUNK + t * SCAN_ITEMS;
  int vals[SCAN_ITEMS]; int ts = 0;
#pragma unroll
  for (int i = 0; i < SCAN_ITEMS; i++) {
    int idx = base + i;
    vals[i] = (idx < N_NODES) ? cnt[idx] : 0;
    ts += vals[i];
  }
  sd[t] = ts; __syncthreads();
  for (int o = 1; o < 256; o <<= 1) {
    int v = 0;
    if (t >= o) v = sd[t - o];
    __syncthreads();
    sd[t] += v;
    __syncthreads();
  }
  int run = boff[b] + sd[t] - ts;
#pragma unroll
  for (int i = 0; i < SCAN_ITEMS; i++) {
    int idx = base + i;
    if (idx < N_NODES) row_ptr[idx] = run;
    run += vals[i];
  }
  if (b == 0 && t == 0) row_ptr[N_NODES] = E_TOT;
  __syncthreads();
}

__device__ __forceinline__ void scatter_unit(int u, int t, const int* ei, const int* row_ptr,
                                             const int* epos, int* colA) {
  int tid = u * 256 + t;
  if (tid < E_TOT) {
    int s, d;
    if (tid < E_EDGES) { s = ei[tid]; d = ei[E_EDGES + tid]; }
    else { s = tid - E_EDGES; d = s; }
    colA[row_ptr[d] + epos[tid]] = s;
  }
}

__device__ __forceinline__ void gemm1_tile(int tile, int tix, const float* x,
                                           const unsigned short* Wt,
                                           unsigned short* Hlb, unsigned short* Hrb) {
  int w = tix >> 6, lane = tix & 63;
  int m = lane & 15, quad = lane >> 4;
  int row0 = tile * 64 + w * 16;
  int arow = row0 + m;
  short8 A[4];
  bool aok = arow < N_NODES;
  const float4* ap = (const float4*)(x + (size_t)arow * FDIM + quad * 8);
#pragma unroll
  for (int c = 0; c < 4; c++) {
    short8 a = {};
    if (aok) {
      float4 v0 = ap[c * 8 + 0];
      float4 v1 = ap[c * 8 + 1];
      a[0] = (short)f2bf(v0.x); a[1] = (short)f2bf(v0.y);
      a[2] = (short)f2bf(v0.z); a[3] = (short)f2bf(v0.w);
      a[4] = (short)f2bf(v1.x); a[5] = (short)f2bf(v1.y);
      a[6] = (short)f2bf(v1.z); a[7] = (short)f2bf(v1.w);
    }
    A[c] = a;
  }
  int orow = row0 + quad * 4;
#pragma unroll
  for (int t0 = 0; t0 < 16; t0++) {
    const short8* bp = (const short8*)(Wt + (size_t)(t0 * 16 + m) * 128 + quad * 8);
    f32x4 acc = {0.f, 0.f, 0.f, 0.f};
#pragma unroll
    for (int c = 0; c < 4; c++)
      acc = __builtin_amdgcn_mfma_f32_16x16x32_bf16(A[c], bp[c * 4], acc, 0, 0, 0);
    int n0 = t0 * 16;
    unsigned short* dst = (n0 < 128) ? Hlb : Hrb;
    int col = (n0 < 128) ? n0 + m : (n0 - 128) + m;
#pragma unroll
    for (int r = 0; r < 4; r++) {
      int row = orow + r;
      if (row < N_NODES) dst[(size_t)row * FDIM + col] = f2bf(acc[r]);
    }
  }
}

// agg1: 1 wave/node, in-wave bitonic sort -> LDS idx, 8-deep gather batches,
// fused ReLU+bias and layer-2 transform. hshp = float[4][FDIM], sidxp = int[4][64].
__device__ __forceinline__ void agg1_unit(int u, int tix, float* hshp, int* sidxp,
                                          const unsigned short* Hlb, const unsigned short* Hrb,
                                          const int* row_ptr, int* colA,
                                          const float* att, const float* bias,
                                          const float* W2l, const float* W2r,
                                          float* yl, float* yr) {
  int w = tix >> 6;
  int node = u * 4 + w;
  if (node >= N_NODES) return;   // per-wave guard; no block syncs below
  int lane = tix & 63;
  int c0 = 2 * lane;
  const unsigned int* Hl32 = (const unsigned int*)Hlb;
  const unsigned int* Hr32 = (const unsigned int*)Hrb;
  float2 xr = up2(Hr32[((size_t)node << 6) + lane]);
  float a0 = att[c0] * LOG2E;
  float a1 = att[c0 + 1] * LOG2E;
  int beg = row_ptr[node], end = row_ptr[node + 1];
  int deg = end - beg;
  bool small = deg <= 64;

  if (small) {
    int v = (lane < deg) ? colA[beg + lane] : 0x7FFFFFFF;
#pragma unroll
    for (int k = 2; k <= 64; k <<= 1) {
#pragma unroll
      for (int j = k >> 1; j > 0; j >>= 1) {
        int other = __shfl_xor(v, j);
        bool up = ((lane & k) == 0);
        bool lower = ((lane & j) == 0);
        int mn = min(v, other), mx = max(v, other);
        v = (lower == up) ? mn : mx;
      }
    }
    sidxp[w * 64 + lane] = v;
    if (lane < deg) colA[beg + lane] = v;   // sorted row for agg2
  } else {
    if (lane == 0) {
      for (int i = beg + 1; i < end; i++) {
        int vv = colA[i];
        int j = i - 1;
        while (j >= beg && colA[j] > vv) { colA[j + 1] = colA[j]; j--; }
        colA[j + 1] = vv;
      }
    }
    __threadfence_block();
  }

  float l = 0.f, ax = 0.f, ay = 0.f;
  auto update = [&](unsigned int v) {
    float2 xl = up2(v);
    float tx = xl.x + xr.x, ty = xl.y + xr.y;
    tx = tx > 0.f ? tx : NEG * tx;
    ty = ty > 0.f ? ty : NEG * ty;
    float p = row16_sum(fmaf(a0, tx, a1 * ty));
    float ww = __builtin_amdgcn_exp2f(fminf(p, PCLAMP));
    l  += ww;
    ax = fmaf(ww, xl.x, ax);
    ay = fmaf(ww, xl.y, ay);
  };

  if (small) {
    const int* si = sidxp + w * 64;
    int j = 0;
    for (; j + 8 <= deg; j += 8) {
      unsigned int v0 = Hl32[((size_t)si[j + 0] << 6) + lane];
      unsigned int v1 = Hl32[((size_t)si[j + 1] << 6) + lane];
      unsigned int v2 = Hl32[((size_t)si[j + 2] << 6) + lane];
      unsigned int v3 = Hl32[((size_t)si[j + 3] << 6) + lane];
      unsigned int v4 = Hl32[((size_t)si[j + 4] << 6) + lane];
      unsigned int v5 = Hl32[((size_t)si[j + 5] << 6) + lane];
      unsigned int v6 = Hl32[((size_t)si[j + 6] << 6) + lane];
      unsigned int v7 = Hl32[((size_t)si[j + 7] << 6) + lane];
      update(v0); update(v1); update(v2); update(v3);
      update(v4); update(v5); update(v6); update(v7);
    }
    for (; j + 2 <= deg; j += 2) {
      unsigned int v0 = Hl32[((size_t)si[j + 0] << 6) + lane];
      unsigned int v1 = Hl32[((size_t)si[j + 1] << 6) + lane];
      update(v0); update(v1);
    }
    if (j < deg) update(Hl32[((size_t)si[j] << 6) + lane]);
  } else {
    for (int j = beg; j < end; j++) update(Hl32[((size_t)colA[j] << 6) + lane]);
  }

  float inv = 1.f / l;
  float ox = fmaxf(fmaf(ax, inv, bias[c0]),     0.f);   // fused ReLU
  float oy = fmaxf(fmaf(ay, inv, bias[c0 + 1]), 0.f);
  hshp[w * FDIM + c0] = ox; hshp[w * FDIM + c0 + 1] = oy;
  if (lane < 2 * C2) {
    bool isl = lane < C2;
    int cc = isl ? lane : lane - C2;
    const float* W = isl ? W2l : W2r;
    float acc = 0.f;
    const float4* h4 = (const float4*)(hshp + w * FDIM);
#pragma unroll
    for (int k4 = 0; k4 < 32; k4++) {
      float4 hv = h4[k4];
      int k = k4 * 4;
      acc = fmaf(hv.x, W[(k + 0) * C2 + cc], acc);
      acc = fmaf(hv.y, W[(k + 1) * C2 + cc], acc);
      acc = fmaf(hv.z, W[(k + 2) * C2 + cc], acc);
      acc = fmaf(hv.w, W[(k + 3) * C2 + cc], acc);
    }
    float* Y = isl ? yl : yr;
    Y[(size_t)node * YPAD + cc] = acc;
  }
}

// agg2: 1 wave/node, 4-way edge-parallel groups, fixed combine tree (deterministic).
__device__ __forceinline__ void agg2_unit(int u, int tix,
                                          const float* yl, const float* yr,
                                          const int* row_ptr, const int* colA,
                                          const float* att, const float* bias,
                                          float* outp) {
  int w = tix >> 6;
  int node = u * 4 + w;
  if (node >= N_NODES) return;
  int lane = tix & 63;
  int ch = lane & 15;
  int g  = lane >> 4;
  bool act = ch < C2;
  float xr = act ? yr[(size_t)node * YPAD + ch] : 0.f;
  float a  = act ? att[ch] * LOG2E : 0.f;
  int beg = row_ptr[node], end = row_ptr[node + 1];
  float l = 0.f, acc = 0.f;
  const float* ylL = yl + (act ? ch : 0);

  auto update = [&](float xl) {
    float t = xl + xr;
    t = t > 0.f ? t : NEG * t;
    float p = row16_sum(a * t);
    float wgt = __builtin_amdgcn_exp2f(fminf(p, PCLAMP));
    l += wgt;
    acc = fmaf(wgt, xl, acc);
  };

  int j = beg + g;
  for (; j + 4 < end; j += 8) {
    int s0 = colA[j], s1 = colA[j + 4];
    float x0 = act ? ylL[(size_t)s0 << 4] : 0.f;
    float x1 = act ? ylL[(size_t)s1 << 4] : 0.f;
    update(x0); update(x1);
  }
  if (j < end) {
    int s0 = colA[j];
    float x0 = act ? ylL[(size_t)s0 << 4] : 0.f;
    update(x0);
  }
  l   += __shfl_xor(l, 16);
  acc += __shfl_xor(acc, 16);
  l   += __shfl_xor(l, 32);
  acc += __shfl_xor(acc, 32);
  if (g == 0 && act) outp[(size_t)node * C2 + ch] = acc / l + bias[ch];
}

// =================== cooperative mega-kernel ===================
__global__ __launch_bounds__(256, 8) void k_mega(
    const float* __restrict__ x, const int* __restrict__ ei,
    const float* __restrict__ W1l, const float* __restrict__ W1r,
    const float* __restrict__ att1, const float* __restrict__ b1,
    const float* __restrict__ W2l, const float* __restrict__ W2r,
    const float* __restrict__ att2, const float* __restrict__ b2,
    float* __restrict__ out,
    unsigned short* __restrict__ Hlb, unsigned short* __restrict__ Hrb,
    unsigned short* __restrict__ Wt,
    float* __restrict__ yl, float* __restrict__ yr,
    int* __restrict__ cnt, int* __restrict__ row_ptr, int* __restrict__ colA,
    int* __restrict__ epos, int* __restrict__ bsum, int* __restrict__ boff) {
  cg::grid_group grid = cg::this_grid();
  __shared__ int   sd[256];
  __shared__ float hsh[4 * FDIM];
  __shared__ int   sidx[4 * 64];
  const int t = threadIdx.x;
  const unsigned gsz = gridDim.x;

  // Phase A: Wt transpose + degree count (independent)
  for (unsigned u = blockIdx.x; u < NWT + NDEG; u += gsz) {
    if (u < NWT) wt_unit(u, t, W1l, W1r, Wt);
    else         deg_unit(u - NWT, t, ei, cnt, epos);
  }
  grid.sync();
  // Phase B: gemm1 (MFMA) + scan1 (independent)
  for (unsigned u = blockIdx.x; u < NT1 + SCAN_NBLK; u += gsz) {
    if (u < NT1) gemm1_tile(u, t, x, Wt, Hlb, Hrb);
    else         scan1_unit(u - NT1, t, cnt, bsum, sd);
  }
  grid.sync();
  // Phase C: scan2 (block 0, wave 0)
  if (blockIdx.x == 0 && t < 64) scan2_unit(t, bsum, boff);
  grid.sync();
  // Phase D: scan3
  for (unsigned u = blockIdx.x; u < SCAN_NBLK; u += gsz) scan3_unit(u, t, cnt, boff, row_ptr, sd);
  grid.sync();
  // Phase E: scatter
  for (unsigned u = blockIdx.x; u < NDEG; u += gsz) scatter_unit(u, t, ei, row_ptr, epos, colA);
  grid.sync();
  // Phase F: layer-1 aggregation (+sort +fused transform)
  for (unsigned u = blockIdx.x; u < NAGG; u += gsz)
    agg1_unit(u, t, hsh, sidx, Hlb, Hrb, row_ptr, colA, att1, b1, W2l, W2r, yl, yr);
  grid.sync();
  // Phase G: layer-2 aggregation
  for (unsigned u = blockIdx.x; u < NAGG; u += gsz)
    agg2_unit(u, t, yl, yr, row_ptr, colA, att2, b2, out);
}

// =================== fallback standalone kernels (R12 sequence) ===================
__global__ __launch_bounds__(256) void k_deg(const int* __restrict__ ei, int* __restrict__ cnt,
                                             int* __restrict__ epos) {
  deg_unit(blockIdx.x, threadIdx.x, ei, cnt, epos);
}
__global__ __launch_bounds__(256) void k_scan1(const int* __restrict__ cnt, int* __restrict__ bsum) {
  __shared__ int sd[256];
  scan1_unit(blockIdx.x, threadIdx.x, cnt, bsum, sd);
}
__global__ __launch_bounds__(64) void k_scan2(const int* __restrict__ bsum, int* __restrict__ boff) {
  scan2_unit(threadIdx.x, bsum, boff);
}
__global__ __launch_bounds__(256) void k_scan3(const int* __restrict__ cnt, const int* __restrict__ boff,
                                               int* __restrict__ row_ptr) {
  __shared__ int sd[256];
  scan3_unit(blockIdx.x, threadIdx.x, cnt, boff, row_ptr, sd);
}
__global__ __launch_bounds__(256) void k_scatter(const int* __restrict__ ei,
                                                 const int* __restrict__ row_ptr,
                                                 const int* __restrict__ epos,
                                                 int* __restrict__ colA) {
  scatter_unit(blockIdx.x, threadIdx.x, ei, row_ptr, epos, colA);
}
__global__ __launch_bounds__(256) void k_wt(const float* __restrict__ W1l, const float* __restrict__ W1r,
                                            unsigned short* __restrict__ Wt) {
  if (blockIdx.x < NWT) wt_unit(blockIdx.x, threadIdx.x, W1l, W1r, Wt);
}
__global__ __launch_bounds__(256) void k_gemm1(const float* __restrict__ x,
                                               const unsigned short* __restrict__ Wt,
                                               unsigned short* __restrict__ Hlb,
                                               unsigned short* __restrict__ Hrb) {
  gemm1_tile(blockIdx.x, threadIdx.x, x, Wt, Hlb, Hrb);
}
__global__ __launch_bounds__(256) void k_agg1(const unsigned short* __restrict__ Hlb,
                                              const unsigned short* __restrict__ Hrb,
                                              const int* __restrict__ row_ptr, int* __restrict__ colA,
                                              const float* __restrict__ att, const float* __restrict__ bias,
                                              const float* __restrict__ W2l, const float* __restrict__ W2r,
                                              float* __restrict__ yl, float* __restrict__ yr) {
  __shared__ float hsh[4 * FDIM];
  __shared__ int sidx[4 * 64];
  agg1_unit(blockIdx.x, threadIdx.x, hsh, sidx, Hlb, Hrb, row_ptr, colA, att, bias, W2l, W2r, yl, yr);
}
__global__ __launch_bounds__(256) void k_agg2(const float* __restrict__ yl, const float* __restrict__ yr,
                                              const int* __restrict__ row_ptr, const int* __restrict__ colA,
                                              const float* __restrict__ att, const float* __restrict__ bias,
                                              float* __restrict__ outp) {
  agg2_unit(blockIdx.x, threadIdx.x, yl, yr, row_ptr, colA, att, bias, outp);
}

extern "C" void kernel_launch(void* const* d_in, const int* in_sizes, int n_in,
                              void* d_out, int out_size, void* d_ws, size_t ws_size,
                              hipStream_t stream) {
  const float* x    = (const float*)d_in[0];
  const int*   ei   = (const int*)d_in[1];
  const float* W1l  = (const float*)d_in[2];
  const float* W1r  = (const float*)d_in[3];
  const float* att1 = (const float*)d_in[4];
  const float* b1   = (const float*)d_in[5];
  const float* W2l  = (const float*)d_in[6];
  const float* W2r  = (const float*)d_in[7];
  const float* att2 = (const float*)d_in[8];
  const float* b2   = (const float*)d_in[9];
  float* out = (float*)d_out;

  char* ws = (char*)d_ws;
  size_t off = 0;
  auto take = [&](size_t bytes) -> char* {
    char* p = ws + off;
    off = (off + bytes + 511) & ~(size_t)511;
    return p;
  };
  unsigned short* Hlb = (unsigned short*)take((size_t)N_NODES * FDIM * sizeof(unsigned short));
  unsigned short* Hrb = (unsigned short*)take((size_t)N_NODES * FDIM * sizeof(unsigned short));
  unsigned short* Wt  = (unsigned short*)take((size_t)256 * 128 * sizeof(unsigned short));
  float* yl      = (float*)take((size_t)N_NODES * YPAD * sizeof(float));
  float* yr      = (float*)take((size_t)N_NODES * YPAD * sizeof(float));
  int*   cnt     = (int*)take((size_t)N_NODES * sizeof(int));
  int*   row_ptr = (int*)take((size_t)(N_NODES + 1) * sizeof(int));
  int*   colA    = (int*)take((size_t)E_TOT * sizeof(int));
  int*   epos    = (int*)take((size_t)E_TOT * sizeof(int));
  int*   bsum    = (int*)take(256);
  int*   boff    = (int*)take(256);
  if (off > ws_size) return;

  (void)hipMemsetAsync(cnt, 0, (size_t)N_NODES * sizeof(int), stream);

  // Try the cooperative mega-kernel (eliminates 8 dispatch boundaries and
  // overlaps gemm1 with the CSR build). Deterministic fallback: R12 sequence
  // (bit-identical output to the mega path).
  bool coop = false;
  int nb = 0;
  if (hipOccupancyMaxActiveBlocksPerMultiprocessor(&nb, k_mega, 256, 0) == hipSuccess && nb > 0) {
    int blocksPerCU = nb < 8 ? nb : 8;
    dim3 grid(blocksPerCU * 256), block(256);
    void* args[] = {
      (void*)&x, (void*)&ei, (void*)&W1l, (void*)&W1r, (void*)&att1, (void*)&b1,
      (void*)&W2l, (void*)&W2r, (void*)&att2, (void*)&b2, (void*)&out,
      (void*)&Hlb, (void*)&Hrb, (void*)&Wt, (void*)&yl, (void*)&yr,
      (void*)&cnt, (void*)&row_ptr, (void*)&colA, (void*)&epos,
      (void*)&bsum, (void*)&boff
    };
    coop = (hipLaunchCooperativeKernel((void*)k_mega, grid, block, args, 0, stream) == hipSuccess);
  }
  if (!coop) {
    k_deg    <<<NDEG, 256, 0, stream>>>(ei, cnt, epos);
    k_scan1  <<<SCAN_NBLK, 256, 0, stream>>>(cnt, bsum);
    k_scan2  <<<1, 64, 0, stream>>>(bsum, boff);
    k_scan3  <<<SCAN_NBLK, 256, 0, stream>>>(cnt, boff, row_ptr);
    k_scatter<<<NDEG, 256, 0, stream>>>(ei, row_ptr, epos, colA);
    k_wt     <<<NWT, 256, 0, stream>>>(W1l, W1r, Wt);
    k_gemm1  <<<NT1, 256, 0, stream>>>(x, Wt, Hlb, Hrb);
    k_agg1   <<<NAGG, 256, 0, stream>>>(Hlb, Hrb, row_ptr, colA, att1, b1, W2l, W2r, yl, yr);
    k_agg2   <<<NAGG, 256, 0, stream>>>(yl, yr, row_ptr, colA, att2, b2, out);
  }
}

// Round 14
// 503.909 us; speedup vs baseline: 3.6439x; 3.6439x over previous
//
#include <hip/hip_runtime.h>

#define N_NODES 100000
#define E_EDGES 1600000
#define E_TOT   1700000   // edges + self loops
#define FDIM    128       // F_IN and HEADS*HID
#define C2      10        // classes
#define YPAD    16        // yl/yr row stride (one 64B line)
#define NEG     0.2f
#define LOG2E   1.44269504088896f
#define PCLAMP  80.0f

#define NDEG    ((E_TOT + 255) / 256)        // 6641 edge chunks
#define NWT     128                          // 32768 / 256

typedef __attribute__((ext_vector_type(8))) short short8;
typedef __attribute__((ext_vector_type(4))) float f32x4;

// 16-lane row reduction via DPP (pure VALU, no LDS pipe)
template <int CTRL>
__device__ __forceinline__ float dpp_add(float x) {
  return x + __int_as_float(
      __builtin_amdgcn_update_dpp(0, __float_as_int(x), CTRL, 0xF, 0xF, true));
}
__device__ __forceinline__ float row16_sum(float p) {
  p = dpp_add<0xB1>(p);
  p = dpp_add<0x4E>(p);
  p = dpp_add<0x141>(p);
  p = dpp_add<0x140>(p);
  return p;
}

// fp32 -> bf16 (round-nearest-even), and packed bf16x2 -> float2
__device__ __forceinline__ unsigned short f2bf(float f) {
  unsigned int u = __float_as_uint(f);
  u += 0x7FFFu + ((u >> 16) & 1u);
  return (unsigned short)(u >> 16);
}
__device__ __forceinline__ float2 up2(unsigned int v) {
  return make_float2(__uint_as_float(v << 16), __uint_as_float(v & 0xFFFF0000u));
}

// ---------------- prep: W1 transpose (blocks 0..127) + degree count (rest) ----------------
__global__ __launch_bounds__(256) void k_prep(const float* __restrict__ W1l, const float* __restrict__ W1r,
                                              unsigned short* __restrict__ Wt,
                                              const int* __restrict__ ei, int* __restrict__ cnt,
                                              int* __restrict__ epos) {
  int b = blockIdx.x;
  if (b < NWT) {
    int i = b * 256 + threadIdx.x;
    int n = i & 255, k = i >> 8;
    float v = (n < 128) ? W1l[k * 128 + n] : W1r[k * 128 + (n - 128)];
    Wt[n * 128 + k] = f2bf(v);   // B^T layout: row n, contiguous k
  } else {
    int tid = (b - NWT) * 256 + threadIdx.x;
    if (tid < E_TOT) {
      int d = (tid < E_EDGES) ? ei[E_EDGES + tid] : (tid - E_EDGES);
      epos[tid] = atomicAdd(&cnt[d], 1);
    }
  }
}

#define SCAN_ITEMS 8
#define SCAN_CHUNK 2048
#define SCAN_NBLK  ((N_NODES + SCAN_CHUNK - 1) / SCAN_CHUNK)   // 49

__global__ __launch_bounds__(256) void k_scan1(const int* __restrict__ cnt, int* __restrict__ bsum) {
  int b = blockIdx.x, t = threadIdx.x;
  int base = b * SCAN_CHUNK + t * SCAN_ITEMS;
  int s = 0;
#pragma unroll
  for (int i = 0; i < SCAN_ITEMS; i++) {
    int idx = base + i;
    if (idx < N_NODES) s += cnt[idx];
  }
  __shared__ int sd[256];
  sd[t] = s; __syncthreads();
  for (int o = 128; o > 0; o >>= 1) {
    if (t < o) sd[t] += sd[t + o];
    __syncthreads();
  }
  if (t == 0) bsum[b] = sd[0];
}

__global__ __launch_bounds__(64) void k_scan2(const int* __restrict__ bsum, int* __restrict__ boff) {
  int t = threadIdx.x;
  int v = (t < SCAN_NBLK) ? bsum[t] : 0;
  int orig = v;
  for (int o = 1; o < 64; o <<= 1) {
    int u = __shfl_up(v, o);
    if (t >= o) v += u;
  }
  if (t < SCAN_NBLK) boff[t] = v - orig;
}

__global__ __launch_bounds__(256) void k_scan3(const int* __restrict__ cnt, const int* __restrict__ boff,
                                               int* __restrict__ row_ptr) {
  int b = blockIdx.x, t = threadIdx.x;
  int base = b * SCAN_CHUNK + t * SCAN_ITEMS;
  int vals[SCAN_ITEMS]; int ts = 0;
#pragma unroll
  for (int i = 0; i < SCAN_ITEMS; i++) {
    int idx = base + i;
    vals[i] = (idx < N_NODES) ? cnt[idx] : 0;
    ts += vals[i];
  }
  __shared__ int sd[256];
  sd[t] = ts; __syncthreads();
  for (int o = 1; o < 256; o <<= 1) {
    int v = 0;
    if (t >= o) v = sd[t - o];
    __syncthreads();
    sd[t] += v;
    __syncthreads();
  }
  int run = boff[b] + sd[t] - ts;
#pragma unroll
  for (int i = 0; i < SCAN_ITEMS; i++) {
    int idx = base + i;
    if (idx < N_NODES) row_ptr[idx] = run;
    run += vals[i];
  }
  if (b == 0 && t == 0) row_ptr[N_NODES] = E_TOT;
}

__global__ __launch_bounds__(256) void k_scatter(const int* __restrict__ ei,
                                                 const int* __restrict__ row_ptr,
                                                 const int* __restrict__ epos,
                                                 int* __restrict__ colA) {
  int tid = blockIdx.x * 256 + threadIdx.x;
  if (tid >= E_TOT) return;
  int s, d;
  if (tid < E_EDGES) { s = ei[tid]; d = ei[E_EDGES + tid]; }
  else { s = tid - E_EDGES; d = s; }
  colA[row_ptr[d] + epos[tid]] = s;
}

// ---------------- Layer-1 GEMM via MFMA: [Hl|Hr] = x @ [W1l|W1r] (bf16 in, fp32 acc) ----------------
__global__ __launch_bounds__(256) void k_gemm1(const float* __restrict__ x,
                                               const unsigned short* __restrict__ Wt,
                                               unsigned short* __restrict__ Hlb,
                                               unsigned short* __restrict__ Hrb) {
  int w = threadIdx.x >> 6, lane = threadIdx.x & 63;
  int m = lane & 15, quad = lane >> 4;
  int row0 = blockIdx.x * 64 + w * 16;
  int arow = row0 + m;
  short8 A[4];
  bool aok = arow < N_NODES;
  const float4* ap = (const float4*)(x + (size_t)arow * FDIM + quad * 8);
#pragma unroll
  for (int c = 0; c < 4; c++) {
    short8 a = {};
    if (aok) {
      float4 v0 = ap[c * 8 + 0];
      float4 v1 = ap[c * 8 + 1];
      a[0] = (short)f2bf(v0.x); a[1] = (short)f2bf(v0.y);
      a[2] = (short)f2bf(v0.z); a[3] = (short)f2bf(v0.w);
      a[4] = (short)f2bf(v1.x); a[5] = (short)f2bf(v1.y);
      a[6] = (short)f2bf(v1.z); a[7] = (short)f2bf(v1.w);
    }
    A[c] = a;
  }

  int orow = row0 + quad * 4;
#pragma unroll
  for (int t0 = 0; t0 < 16; t0++) {
    const short8* bp = (const short8*)(Wt + (size_t)(t0 * 16 + m) * 128 + quad * 8);
    f32x4 acc = {0.f, 0.f, 0.f, 0.f};
#pragma unroll
    for (int c = 0; c < 4; c++)
      acc = __builtin_amdgcn_mfma_f32_16x16x32_bf16(A[c], bp[c * 4], acc, 0, 0, 0);
    int n0 = t0 * 16;
    unsigned short* dst = (n0 < 128) ? Hlb : Hrb;
    int col = (n0 < 128) ? n0 + m : (n0 - 128) + m;
#pragma unroll
    for (int r = 0; r < 4; r++) {
      int row = orow + r;
      if (row < N_NODES) dst[(size_t)row * FDIM + col] = f2bf(acc[r]);
    }
  }
}

// ---------------- Layer-1 aggregation + in-wave CSR sort + fused layer-2 transform ----------------
__global__ __launch_bounds__(256) void k_agg1(const unsigned short* __restrict__ Hlb,
                                              const unsigned short* __restrict__ Hrb,
                                              const int* __restrict__ row_ptr, int* __restrict__ colA,
                                              const float* __restrict__ att, const float* __restrict__ bias,
                                              const float* __restrict__ W2l, const float* __restrict__ W2r,
                                              float* __restrict__ yl, float* __restrict__ yr) {
  __shared__ float hsh[4][FDIM];
  __shared__ int sidx[4][64];
  int w = threadIdx.x >> 6;
  int node = blockIdx.x * 4 + w;
  if (node >= N_NODES) return;
  int lane = threadIdx.x & 63;
  int c0 = 2 * lane;
  const unsigned int* Hl32 = (const unsigned int*)Hlb;   // row = 64 uints
  const unsigned int* Hr32 = (const unsigned int*)Hrb;
  float2 xr = up2(Hr32[((size_t)node << 6) + lane]);
  float a0 = att[c0] * LOG2E;
  float a1 = att[c0 + 1] * LOG2E;
  int beg = row_ptr[node], end = row_ptr[node + 1];
  int deg = end - beg;
  bool small = deg <= 64;

  if (small) {
    // in-wave bitonic sort (canonical ascending order -> deterministic FP order)
    int v = (lane < deg) ? colA[beg + lane] : 0x7FFFFFFF;
#pragma unroll
    for (int k = 2; k <= 64; k <<= 1) {
#pragma unroll
      for (int j = k >> 1; j > 0; j >>= 1) {
        int other = __shfl_xor(v, j);
        bool up = ((lane & k) == 0);
        bool lower = ((lane & j) == 0);
        int mn = min(v, other), mx = max(v, other);
        v = (lower == up) ? mn : mx;
      }
    }
    sidx[w][lane] = v;                      // intra-wave: DS ops in order
    if (lane < deg) colA[beg + lane] = v;   // sorted row for agg2
  } else {
    if (lane == 0) {
      for (int i = beg + 1; i < end; i++) {
        int vv = colA[i];
        int j = i - 1;
        while (j >= beg && colA[j] > vv) { colA[j + 1] = colA[j]; j--; }
        colA[j + 1] = vv;
      }
    }
    __threadfence_block();
  }

  float l = 0.f, ax = 0.f, ay = 0.f;
  auto update = [&](unsigned int v) {
    float2 xl = up2(v);
    float tx = xl.x + xr.x, ty = xl.y + xr.y;
    tx = tx > 0.f ? tx : NEG * tx;
    ty = ty > 0.f ? ty : NEG * ty;
    float p = row16_sum(fmaf(a0, tx, a1 * ty));
    float ww = __builtin_amdgcn_exp2f(fminf(p, PCLAMP));
    l  += ww;
    ax = fmaf(ww, xl.x, ax);
    ay = fmaf(ww, xl.y, ay);
  };

  if (small) {
    const int* si = sidx[w];
    int j = 0;
    for (; j + 8 <= deg; j += 8) {
      unsigned int v0 = Hl32[((size_t)si[j + 0] << 6) + lane];
      unsigned int v1 = Hl32[((size_t)si[j + 1] << 6) + lane];
      unsigned int v2 = Hl32[((size_t)si[j + 2] << 6) + lane];
      unsigned int v3 = Hl32[((size_t)si[j + 3] << 6) + lane];
      unsigned int v4 = Hl32[((size_t)si[j + 4] << 6) + lane];
      unsigned int v5 = Hl32[((size_t)si[j + 5] << 6) + lane];
      unsigned int v6 = Hl32[((size_t)si[j + 6] << 6) + lane];
      unsigned int v7 = Hl32[((size_t)si[j + 7] << 6) + lane];
      update(v0); update(v1); update(v2); update(v3);
      update(v4); update(v5); update(v6); update(v7);
    }
    for (; j + 2 <= deg; j += 2) {
      unsigned int v0 = Hl32[((size_t)si[j + 0] << 6) + lane];
      unsigned int v1 = Hl32[((size_t)si[j + 1] << 6) + lane];
      update(v0); update(v1);
    }
    if (j < deg) update(Hl32[((size_t)si[j] << 6) + lane]);
  } else {
    for (int j = beg; j < end; j++) update(Hl32[((size_t)colA[j] << 6) + lane]);
  }

  float inv = 1.f / l;
  float ox = fmaxf(fmaf(ax, inv, bias[c0]),     0.f);   // fused ReLU
  float oy = fmaxf(fmaf(ay, inv, bias[c0 + 1]), 0.f);
  hsh[w][c0] = ox; hsh[w][c0 + 1] = oy;
  if (lane < 2 * C2) {
    bool isl = lane < C2;
    int cc = isl ? lane : lane - C2;
    const float* W = isl ? W2l : W2r;
    float acc = 0.f;
    const float4* h4 = (const float4*)hsh[w];
#pragma unroll
    for (int k4 = 0; k4 < 32; k4++) {
      float4 hv = h4[k4];
      int k = k4 * 4;
      acc = fmaf(hv.x, W[(k + 0) * C2 + cc], acc);
      acc = fmaf(hv.y, W[(k + 1) * C2 + cc], acc);
      acc = fmaf(hv.z, W[(k + 2) * C2 + cc], acc);
      acc = fmaf(hv.w, W[(k + 3) * C2 + cc], acc);
    }
    float* Y = isl ? yl : yr;
    Y[(size_t)node * YPAD + cc] = acc;
  }
}

// ---------------- Layer-2 aggregation: 1 wave/node, 4-way edge-parallel ----------------
__global__ __launch_bounds__(256) void k_agg2(const float* __restrict__ yl, const float* __restrict__ yr,
                                              const int* __restrict__ row_ptr, const int* __restrict__ colA,
                                              const float* __restrict__ att, const float* __restrict__ bias,
                                              float* __restrict__ outp) {
  int w = threadIdx.x >> 6;
  int node = blockIdx.x * 4 + w;
  if (node >= N_NODES) return;
  int lane = threadIdx.x & 63;
  int ch = lane & 15;
  int g  = lane >> 4;
  bool act = ch < C2;
  float xr = act ? yr[(size_t)node * YPAD + ch] : 0.f;
  float a  = act ? att[ch] * LOG2E : 0.f;
  int beg = row_ptr[node], end = row_ptr[node + 1];
  float l = 0.f, acc = 0.f;
  const float* ylL = yl + (act ? ch : 0);

  auto update = [&](float xl) {
    float t = xl + xr;
    t = t > 0.f ? t : NEG * t;
    float p = row16_sum(a * t);                 // 16-lane group reduce
    float wgt = __builtin_amdgcn_exp2f(fminf(p, PCLAMP));
    l += wgt;
    acc = fmaf(wgt, xl, acc);
  };

  int j = beg + g;
  for (; j + 4 < end; j += 8) {                 // 2 edges of this group: j, j+4
    int s0 = colA[j], s1 = colA[j + 4];
    float x0 = act ? ylL[(size_t)s0 << 4] : 0.f;
    float x1 = act ? ylL[(size_t)s1 << 4] : 0.f;
    update(x0); update(x1);
  }
  if (j < end) {
    int s0 = colA[j];
    float x0 = act ? ylL[(size_t)s0 << 4] : 0.f;
    update(x0);
  }

  // fixed combine tree across groups (deterministic): (g0+g1)+(g2+g3)
  l   += __shfl_xor(l, 16);
  acc += __shfl_xor(acc, 16);
  l   += __shfl_xor(l, 32);
  acc += __shfl_xor(acc, 32);
  if (g == 0 && act) outp[(size_t)node * C2 + ch] = acc / l + bias[ch];
}

extern "C" void kernel_launch(void* const* d_in, const int* in_sizes, int n_in,
                              void* d_out, int out_size, void* d_ws, size_t ws_size,
                              hipStream_t stream) {
  const float* x    = (const float*)d_in[0];
  const int*   ei   = (const int*)d_in[1];
  const float* W1l  = (const float*)d_in[2];
  const float* W1r  = (const float*)d_in[3];
  const float* att1 = (const float*)d_in[4];
  const float* b1   = (const float*)d_in[5];
  const float* W2l  = (const float*)d_in[6];
  const float* W2r  = (const float*)d_in[7];
  const float* att2 = (const float*)d_in[8];
  const float* b2   = (const float*)d_in[9];
  float* out = (float*)d_out;

  char* ws = (char*)d_ws;
  size_t off = 0;
  auto take = [&](size_t bytes) -> char* {
    char* p = ws + off;
    off = (off + bytes + 511) & ~(size_t)511;
    return p;
  };
  unsigned short* Hlb = (unsigned short*)take((size_t)N_NODES * FDIM * sizeof(unsigned short)); // 25.6 MB
  unsigned short* Hrb = (unsigned short*)take((size_t)N_NODES * FDIM * sizeof(unsigned short)); // 25.6 MB
  unsigned short* Wt  = (unsigned short*)take((size_t)256 * 128 * sizeof(unsigned short));      // 64 KB
  float* yl      = (float*)take((size_t)N_NODES * YPAD * sizeof(float));   // 6.4 MB
  float* yr      = (float*)take((size_t)N_NODES * YPAD * sizeof(float));   // 6.4 MB
  int*   cnt     = (int*)take((size_t)N_NODES * sizeof(int));
  int*   row_ptr = (int*)take((size_t)(N_NODES + 1) * sizeof(int));
  int*   colA    = (int*)take((size_t)E_TOT * sizeof(int));
  int*   epos    = (int*)take((size_t)E_TOT * sizeof(int));
  int*   bsum    = (int*)take(256);
  int*   boff    = (int*)take(256);
  if (off > ws_size) return;

  (void)hipMemsetAsync(cnt, 0, (size_t)N_NODES * sizeof(int), stream);
  k_prep   <<<NWT + NDEG, 256, 0, stream>>>(W1l, W1r, Wt, ei, cnt, epos);
  k_scan1  <<<SCAN_NBLK, 256, 0, stream>>>(cnt, bsum);
  k_scan2  <<<1, 64, 0, stream>>>(bsum, boff);
  k_scan3  <<<SCAN_NBLK, 256, 0, stream>>>(cnt, boff, row_ptr);
  k_scatter<<<(E_TOT + 255) / 256, 256, 0, stream>>>(ei, row_ptr, epos, colA);
  k_gemm1  <<<(N_NODES + 63) / 64, 256, 0, stream>>>(x, Wt, Hlb, Hrb);
  k_agg1   <<<(N_NODES + 3) / 4, 256, 0, stream>>>(Hlb, Hrb, row_ptr, colA, att1, b1, W2l, W2r, yl, yr);
  k_agg2   <<<(N_NODES + 3) / 4, 256, 0, stream>>>(yl, yr, row_ptr, colA, att2, b2, out);
}